// Round 4
// baseline (151.340 us; speedup 1.0000x reference)
//
#include <hip/hip_runtime.h>
#include <math.h>

// out[b,i,j,f] = min_{di,dj,c} ( x[b,i+di,j+dj,c] - W[di,dj,c,f] )
// x: (16,128,128,16) f32, W: (3,3,16,32) f32, out: (16,126,126,32) f32
//
// R4: fp16 pre-converted x (d_ws) + packed-fp16 min-plus math (irreducible
// 36 pk_sub + ~35 pk_min per wave-iter). Grid sized for exactly ONE full
// residency round: 2048 blocks = 8 blocks/CU = 32 waves/CU (VGPR<=64 via
// __launch_bounds__(256,8)). TI=32 rows/block, dynamic tail (last block 30).

#define TI 32  // output rows per block; 126 = 32+32+32+30

typedef _Float16 h2 __attribute__((ext_vector_type(2)));

__device__ __forceinline__ h2 hmin2(h2 a, h2 b) {
    return __builtin_elementwise_min(a, b);  // v_pk_min_f16
}

__device__ __forceinline__ h2 pkrtz(float a, float b) {
    auto r = __builtin_amdgcn_cvt_pkrtz(a, b);  // v_cvt_pkrtz_f16_f32
    return *reinterpret_cast<h2*>(&r);
}

// min over 12 half2 of (hx[k] - w[k]) for one weight row di
__device__ __forceinline__ h2 rowmin(const h2* hx, const h2 w[3][4]) {
    h2 t[12];
#pragma unroll
    for (int dj = 0; dj < 3; ++dj)
#pragma unroll
        for (int q = 0; q < 4; ++q)
            t[dj * 4 + q] = hx[dj * 4 + q] - w[dj][q];  // v_pk_add_f16 neg
#pragma unroll
    for (int k = 0; k < 6; ++k) t[k] = hmin2(t[k], t[k + 6]);
    t[0] = hmin2(t[0], t[3]);
    t[1] = hmin2(t[1], t[4]);
    t[2] = hmin2(t[2], t[5]);
    return hmin2(hmin2(t[0], t[1]), t[2]);
}

// ---- pre-pass: x fp32 -> fp16, same layout ----
__global__ __launch_bounds__(256) void cvt_kernel(const float* __restrict__ x,
                                                  _Float16* __restrict__ xh) {
    int idx = (blockIdx.x * 256 + threadIdx.x) * 8;
    float4 a = *reinterpret_cast<const float4*>(x + idx);
    float4 b = *reinterpret_cast<const float4*>(x + idx + 4);
    h2 o[4] = { pkrtz(a.x, a.y), pkrtz(a.z, a.w), pkrtz(b.x, b.y), pkrtz(b.z, b.w) };
    *reinterpret_cast<float4*>(xh + idx) = *reinterpret_cast<float4*>(o);
}

// ---- main kernel, fp16 pre-converted input ----
__global__ __launch_bounds__(256, 8) void erosion_h_kernel(
    const _Float16* __restrict__ xh, const float* __restrict__ Wt,
    float* __restrict__ out)
{
    const int tid = threadIdx.x;
    const int f  = tid & 31;
    const int ch = (tid >> 5) & 1;   // channel half: 0 -> c 0..7, 1 -> c 8..15
    const int jt = tid >> 6;         // column in block (wave-uniform)
    const int b  = blockIdx.z;
    const int i0 = blockIdx.y * TI;
    const int rows = min(TI, 126 - i0);   // 32,32,32,30
    int j = blockIdx.x * 4 + jt;     // 0..127
    const bool jvalid = (j < 126);
    if (!jvalid) j = 125;            // clamp so loads stay in bounds

    // wh[di][dj][q] = { W[di,dj, ch*8+2q, f], W[di,dj, ch*8+2q+1, f] } as fp16
    h2 wh[3][3][4];
#pragma unroll
    for (int di = 0; di < 3; ++di)
#pragma unroll
        for (int dj = 0; dj < 3; ++dj)
#pragma unroll
            for (int q = 0; q < 4; ++q) {
                int p = di * 3 + dj;
                float a = Wt[(p * 16 + ch * 8 + 2 * q) * 32 + f];
                float c = Wt[(p * 16 + ch * 8 + 2 * q + 1) * 32 + f];
                wh[di][dj][q] = pkrtz(a, c);
            }

    const _Float16* xb = xh + ((size_t)b * 128 * 128 + (size_t)j) * 16 + ch * 8;
    float* op = out + (((size_t)b * 126 + i0) * 126 + j) * 32 + f;

    const _Float16 HINF = (_Float16)__builtin_huge_valf();
    h2 accB = {HINF, HINF};  // partial min for output row r-1
    h2 accC = {HINF, HINF};  // partial min for output row r-2

#pragma unroll 2
    for (int r = 0; r < rows + 2; ++r) {   // loads reach row i0+rows+1 <= 127
        const _Float16* xr = xb + (size_t)(i0 + r) * 2048;  // 128*16 halves/row
        h2 hx[12];
#pragma unroll
        for (int dj = 0; dj < 3; ++dj) {
            float4 raw = *reinterpret_cast<const float4*>(xr + dj * 16);
            const h2* p = reinterpret_cast<const h2*>(&raw);
            hx[dj * 4 + 0] = p[0];
            hx[dj * 4 + 1] = p[1];
            hx[dj * 4 + 2] = p[2];
            hx[dj * 4 + 3] = p[3];
        }

        h2 n0 = rowmin(hx, wh[0]);
        h2 n1 = rowmin(hx, wh[1]);
        h2 n2 = rowmin(hx, wh[2]);

        h2 fin2 = hmin2(accC, n2);  // output row r-2 complete
        accC = hmin2(accB, n1);
        accB = n0;

        if (r >= 2) {
            _Float16 vm = fin2[0] < fin2[1] ? fin2[0] : fin2[1];  // v_min_f16
            float v = (float)vm;
            v = fminf(v, __shfl_xor(v, 32));  // merge c-halves (lanes tid, tid^32)
            if (jvalid && ch == 0)
                op[(size_t)(r - 2) * (126 * 32)] = v;
        }
    }
}

// ---- fallback (ws too small): in-kernel conversion ----
__global__ __launch_bounds__(256, 8) void erosion_kernel(
    const float* __restrict__ x, const float* __restrict__ Wt,
    float* __restrict__ out)
{
    const int tid = threadIdx.x;
    const int f  = tid & 31;
    const int ch = (tid >> 5) & 1;
    const int jt = tid >> 6;
    const int b  = blockIdx.z;
    const int i0 = blockIdx.y * TI;
    const int rows = min(TI, 126 - i0);
    int j = blockIdx.x * 4 + jt;
    const bool jvalid = (j < 126);
    if (!jvalid) j = 125;

    h2 wh[3][3][4];
#pragma unroll
    for (int di = 0; di < 3; ++di)
#pragma unroll
        for (int dj = 0; dj < 3; ++dj)
#pragma unroll
            for (int q = 0; q < 4; ++q) {
                int p = di * 3 + dj;
                float a = Wt[(p * 16 + ch * 8 + 2 * q) * 32 + f];
                float c = Wt[(p * 16 + ch * 8 + 2 * q + 1) * 32 + f];
                wh[di][dj][q] = pkrtz(a, c);
            }

    const float* xb = x + ((size_t)b * 128 * 128 + (size_t)j) * 16 + ch * 8;
    float* op = out + (((size_t)b * 126 + i0) * 126 + j) * 32 + f;

    const _Float16 HINF = (_Float16)__builtin_huge_valf();
    h2 accB = {HINF, HINF};
    h2 accC = {HINF, HINF};

#pragma unroll 2
    for (int r = 0; r < rows + 2; ++r) {
        const float* xr = xb + (size_t)(i0 + r) * 2048;
        h2 hx[12];
#pragma unroll
        for (int dj = 0; dj < 3; ++dj) {
            float4 lo = *reinterpret_cast<const float4*>(xr + dj * 16);
            float4 hi = *reinterpret_cast<const float4*>(xr + dj * 16 + 4);
            hx[dj * 4 + 0] = pkrtz(lo.x, lo.y);
            hx[dj * 4 + 1] = pkrtz(lo.z, lo.w);
            hx[dj * 4 + 2] = pkrtz(hi.x, hi.y);
            hx[dj * 4 + 3] = pkrtz(hi.z, hi.w);
        }

        h2 n0 = rowmin(hx, wh[0]);
        h2 n1 = rowmin(hx, wh[1]);
        h2 n2 = rowmin(hx, wh[2]);

        h2 fin2 = hmin2(accC, n2);
        accC = hmin2(accB, n1);
        accB = n0;

        if (r >= 2) {
            _Float16 vm = fin2[0] < fin2[1] ? fin2[0] : fin2[1];
            float v = (float)vm;
            v = fminf(v, __shfl_xor(v, 32));
            if (jvalid && ch == 0)
                op[(size_t)(r - 2) * (126 * 32)] = v;
        }
    }
}

extern "C" void kernel_launch(void* const* d_in, const int* in_sizes, int n_in,
                              void* d_out, int out_size, void* d_ws, size_t ws_size,
                              hipStream_t stream) {
    const float* x  = (const float*)d_in[0];  // 16*128*128*16
    const float* Wt = (const float*)d_in[1];  // 3*3*16*32
    float* out = (float*)d_out;               // 16*126*126*32

    const size_t xelems = (size_t)16 * 128 * 128 * 16;  // 4,194,304
    dim3 grid(32, 4, 16);   // 2048 blocks = 8/CU: one full-residency round
    dim3 block(256);

    if (ws_size >= xelems * sizeof(_Float16)) {
        _Float16* xh = (_Float16*)d_ws;
        cvt_kernel<<<dim3(xelems / (256 * 8)), block, 0, stream>>>(x, xh);
        erosion_h_kernel<<<grid, block, 0, stream>>>(xh, Wt, out);
    } else {
        erosion_kernel<<<grid, block, 0, stream>>>(x, Wt, out);
    }
}

// Round 5
// 126.763 us; speedup vs baseline: 1.1939x; 1.1939x over previous
//
#include <hip/hip_runtime.h>
#include <math.h>

// out[b,i,j,f] = min_{di,dj,c} ( x[b,i+di,j+dj,c] - W[di,dj,c,f] )
// x: (16,128,128,16) f32, W: (3,3,16,32) f32, out: (16,126,126,32) f32
//
// R5: R4's one-full-round grid (2048 blocks = 8/CU) WITHOUT the forced
// __launch_bounds__ register cap -- R4's (256,8) cap spilled the 36-reg W
// array to scratch (VGPR 56->32, +33MB phantom HBM traffic, 54->88us).
// Natural allocation is ~56 VGPR which already fits 8 waves/EU.

#define TI 32  // output rows per block; 126 = 32+32+32+30

typedef _Float16 h2 __attribute__((ext_vector_type(2)));

__device__ __forceinline__ h2 hmin2(h2 a, h2 b) {
    return __builtin_elementwise_min(a, b);  // v_pk_min_f16
}

__device__ __forceinline__ h2 pkrtz(float a, float b) {
    auto r = __builtin_amdgcn_cvt_pkrtz(a, b);  // v_cvt_pkrtz_f16_f32
    return *reinterpret_cast<h2*>(&r);
}

// min over 12 half2 of (hx[k] - w[k]) for one weight row di
__device__ __forceinline__ h2 rowmin(const h2* hx, const h2 w[3][4]) {
    h2 t[12];
#pragma unroll
    for (int dj = 0; dj < 3; ++dj)
#pragma unroll
        for (int q = 0; q < 4; ++q)
            t[dj * 4 + q] = hx[dj * 4 + q] - w[dj][q];  // v_pk_add_f16 neg
#pragma unroll
    for (int k = 0; k < 6; ++k) t[k] = hmin2(t[k], t[k + 6]);
    t[0] = hmin2(t[0], t[3]);
    t[1] = hmin2(t[1], t[4]);
    t[2] = hmin2(t[2], t[5]);
    return hmin2(hmin2(t[0], t[1]), t[2]);
}

// ---- pre-pass: x fp32 -> fp16, same layout ----
__global__ __launch_bounds__(256) void cvt_kernel(const float* __restrict__ x,
                                                  _Float16* __restrict__ xh) {
    int idx = (blockIdx.x * 256 + threadIdx.x) * 8;
    float4 a = *reinterpret_cast<const float4*>(x + idx);
    float4 b = *reinterpret_cast<const float4*>(x + idx + 4);
    h2 o[4] = { pkrtz(a.x, a.y), pkrtz(a.z, a.w), pkrtz(b.x, b.y), pkrtz(b.z, b.w) };
    *reinterpret_cast<float4*>(xh + idx) = *reinterpret_cast<float4*>(o);
}

// ---- main kernel, fp16 pre-converted input ----
__global__ __launch_bounds__(256) void erosion_h_kernel(
    const _Float16* __restrict__ xh, const float* __restrict__ Wt,
    float* __restrict__ out)
{
    const int tid = threadIdx.x;
    const int f  = tid & 31;
    const int ch = (tid >> 5) & 1;   // channel half: 0 -> c 0..7, 1 -> c 8..15
    const int jt = tid >> 6;         // column in block (wave-uniform)
    const int b  = blockIdx.z;
    const int i0 = blockIdx.y * TI;
    const int rows = min(TI, 126 - i0);   // 32,32,32,30
    int j = blockIdx.x * 4 + jt;     // 0..127
    const bool jvalid = (j < 126);
    if (!jvalid) j = 125;            // clamp so loads stay in bounds

    // wh[di][dj][q] = { W[di,dj, ch*8+2q, f], W[di,dj, ch*8+2q+1, f] } as fp16
    h2 wh[3][3][4];
#pragma unroll
    for (int di = 0; di < 3; ++di)
#pragma unroll
        for (int dj = 0; dj < 3; ++dj)
#pragma unroll
            for (int q = 0; q < 4; ++q) {
                int p = di * 3 + dj;
                float a = Wt[(p * 16 + ch * 8 + 2 * q) * 32 + f];
                float c = Wt[(p * 16 + ch * 8 + 2 * q + 1) * 32 + f];
                wh[di][dj][q] = pkrtz(a, c);
            }

    const _Float16* xb = xh + ((size_t)b * 128 * 128 + (size_t)j) * 16 + ch * 8;
    float* op = out + (((size_t)b * 126 + i0) * 126 + j) * 32 + f;

    const _Float16 HINF = (_Float16)__builtin_huge_valf();
    h2 accB = {HINF, HINF};  // partial min for output row r-1
    h2 accC = {HINF, HINF};  // partial min for output row r-2

#pragma unroll 2
    for (int r = 0; r < rows + 2; ++r) {   // loads reach row i0+rows+1 <= 127
        const _Float16* xr = xb + (size_t)(i0 + r) * 2048;  // 128*16 halves/row
        h2 hx[12];
#pragma unroll
        for (int dj = 0; dj < 3; ++dj) {
            float4 raw = *reinterpret_cast<const float4*>(xr + dj * 16);
            const h2* p = reinterpret_cast<const h2*>(&raw);
            hx[dj * 4 + 0] = p[0];
            hx[dj * 4 + 1] = p[1];
            hx[dj * 4 + 2] = p[2];
            hx[dj * 4 + 3] = p[3];
        }

        h2 n0 = rowmin(hx, wh[0]);
        h2 n1 = rowmin(hx, wh[1]);
        h2 n2 = rowmin(hx, wh[2]);

        h2 fin2 = hmin2(accC, n2);  // output row r-2 complete
        accC = hmin2(accB, n1);
        accB = n0;

        if (r >= 2) {
            _Float16 vm = fin2[0] < fin2[1] ? fin2[0] : fin2[1];  // v_min_f16
            float v = (float)vm;
            v = fminf(v, __shfl_xor(v, 32));  // merge c-halves (lanes tid, tid^32)
            if (jvalid && ch == 0)
                op[(size_t)(r - 2) * (126 * 32)] = v;
        }
    }
}

// ---- fallback (ws too small): in-kernel conversion ----
__global__ __launch_bounds__(256) void erosion_kernel(
    const float* __restrict__ x, const float* __restrict__ Wt,
    float* __restrict__ out)
{
    const int tid = threadIdx.x;
    const int f  = tid & 31;
    const int ch = (tid >> 5) & 1;
    const int jt = tid >> 6;
    const int b  = blockIdx.z;
    const int i0 = blockIdx.y * TI;
    const int rows = min(TI, 126 - i0);
    int j = blockIdx.x * 4 + jt;
    const bool jvalid = (j < 126);
    if (!jvalid) j = 125;

    h2 wh[3][3][4];
#pragma unroll
    for (int di = 0; di < 3; ++di)
#pragma unroll
        for (int dj = 0; dj < 3; ++dj)
#pragma unroll
            for (int q = 0; q < 4; ++q) {
                int p = di * 3 + dj;
                float a = Wt[(p * 16 + ch * 8 + 2 * q) * 32 + f];
                float c = Wt[(p * 16 + ch * 8 + 2 * q + 1) * 32 + f];
                wh[di][dj][q] = pkrtz(a, c);
            }

    const float* xb = x + ((size_t)b * 128 * 128 + (size_t)j) * 16 + ch * 8;
    float* op = out + (((size_t)b * 126 + i0) * 126 + j) * 32 + f;

    const _Float16 HINF = (_Float16)__builtin_huge_valf();
    h2 accB = {HINF, HINF};
    h2 accC = {HINF, HINF};

#pragma unroll 2
    for (int r = 0; r < rows + 2; ++r) {
        const float* xr = xb + (size_t)(i0 + r) * 2048;
        h2 hx[12];
#pragma unroll
        for (int dj = 0; dj < 3; ++dj) {
            float4 lo = *reinterpret_cast<const float4*>(xr + dj * 16);
            float4 hi = *reinterpret_cast<const float4*>(xr + dj * 16 + 4);
            hx[dj * 4 + 0] = pkrtz(lo.x, lo.y);
            hx[dj * 4 + 1] = pkrtz(lo.z, lo.w);
            hx[dj * 4 + 2] = pkrtz(hi.x, hi.y);
            hx[dj * 4 + 3] = pkrtz(hi.z, hi.w);
        }

        h2 n0 = rowmin(hx, wh[0]);
        h2 n1 = rowmin(hx, wh[1]);
        h2 n2 = rowmin(hx, wh[2]);

        h2 fin2 = hmin2(accC, n2);
        accC = hmin2(accB, n1);
        accB = n0;

        if (r >= 2) {
            _Float16 vm = fin2[0] < fin2[1] ? fin2[0] : fin2[1];
            float v = (float)vm;
            v = fminf(v, __shfl_xor(v, 32));
            if (jvalid && ch == 0)
                op[(size_t)(r - 2) * (126 * 32)] = v;
        }
    }
}

extern "C" void kernel_launch(void* const* d_in, const int* in_sizes, int n_in,
                              void* d_out, int out_size, void* d_ws, size_t ws_size,
                              hipStream_t stream) {
    const float* x  = (const float*)d_in[0];  // 16*128*128*16
    const float* Wt = (const float*)d_in[1];  // 3*3*16*32
    float* out = (float*)d_out;               // 16*126*126*32

    const size_t xelems = (size_t)16 * 128 * 128 * 16;  // 4,194,304
    dim3 grid(32, 4, 16);   // 2048 blocks = 8/CU: one full-residency round
    dim3 block(256);

    if (ws_size >= xelems * sizeof(_Float16)) {
        _Float16* xh = (_Float16*)d_ws;
        cvt_kernel<<<dim3(xelems / (256 * 8)), block, 0, stream>>>(x, xh);
        erosion_h_kernel<<<grid, block, 0, stream>>>(xh, Wt, out);
    } else {
        erosion_kernel<<<grid, block, 0, stream>>>(x, Wt, out);
    }
}

// Round 6
// 117.440 us; speedup vs baseline: 1.2887x; 1.0794x over previous
//
#include <hip/hip_runtime.h>
#include <math.h>

// out[b,i,j,f] = min_{di,dj,c} ( x[b,i+di,j+dj,c] - W[di,dj,c,f] )
// x: (16,128,128,16) f32, W: (3,3,16,32) f32, out: (16,126,126,32) f32
//
// R6: back to R3's proven grid (TI=21, 3072 blocks, static bounds) +
// explicit software prefetch: row r+1's 3 dwordx4 issue BEFORE row r's
// ~71-inst packed-fp16 math, giving a full iteration of latency cover.
// First 2 rows peeled (no store branch in steady loop), last row peeled
// (no prefetch -> no clamp, no OOB). No __launch_bounds__ cap (R4: a
// forced cap spilled W to scratch, +33MB phantom traffic).

#define TI 21  // output rows per block; 126 = 21*6

typedef _Float16 h2 __attribute__((ext_vector_type(2)));

__device__ __forceinline__ h2 hmin2(h2 a, h2 b) {
    return __builtin_elementwise_min(a, b);  // v_pk_min_f16
}

__device__ __forceinline__ h2 pkrtz(float a, float b) {
    auto r = __builtin_amdgcn_cvt_pkrtz(a, b);  // v_cvt_pkrtz_f16_f32
    return *reinterpret_cast<h2*>(&r);
}

// min over 12 half2 of (hx[k] - w[k]) for one weight row di
__device__ __forceinline__ h2 rowmin(const h2* hx, const h2 w[3][4]) {
    h2 t[12];
#pragma unroll
    for (int dj = 0; dj < 3; ++dj)
#pragma unroll
        for (int q = 0; q < 4; ++q)
            t[dj * 4 + q] = hx[dj * 4 + q] - w[dj][q];  // v_pk_add_f16 neg
#pragma unroll
    for (int k = 0; k < 6; ++k) t[k] = hmin2(t[k], t[k + 6]);
    t[0] = hmin2(t[0], t[3]);
    t[1] = hmin2(t[1], t[4]);
    t[2] = hmin2(t[2], t[5]);
    return hmin2(hmin2(t[0], t[1]), t[2]);
}

// ---- pre-pass: x fp32 -> fp16, same layout ----
__global__ __launch_bounds__(256) void cvt_kernel(const float* __restrict__ x,
                                                  _Float16* __restrict__ xh) {
    int idx = (blockIdx.x * 256 + threadIdx.x) * 8;
    float4 a = *reinterpret_cast<const float4*>(x + idx);
    float4 b = *reinterpret_cast<const float4*>(x + idx + 4);
    h2 o[4] = { pkrtz(a.x, a.y), pkrtz(a.z, a.w), pkrtz(b.x, b.y), pkrtz(b.z, b.w) };
    *reinterpret_cast<float4*>(xh + idx) = *reinterpret_cast<float4*>(o);
}

// ---- main kernel: fp16 input, software-pipelined rolling window ----
__global__ __launch_bounds__(256) void erosion_h_kernel(
    const _Float16* __restrict__ xh, const float* __restrict__ Wt,
    float* __restrict__ out)
{
    const int tid = threadIdx.x;
    const int f  = tid & 31;
    const int ch = (tid >> 5) & 1;   // channel half: 0 -> c 0..7, 1 -> c 8..15
    const int jt = tid >> 6;         // column in block (wave-uniform)
    const int b  = blockIdx.z;
    const int i0 = blockIdx.y * TI;
    int j = blockIdx.x * 4 + jt;     // 0..127
    const bool jvalid = (j < 126);
    if (!jvalid) j = 125;            // clamp so loads stay in bounds
    const bool writer = jvalid && (ch == 0);

    // wh[di][dj][q] = { W[di,dj, ch*8+2q, f], W[di,dj, ch*8+2q+1, f] } as fp16
    h2 wh[3][3][4];
#pragma unroll
    for (int di = 0; di < 3; ++di)
#pragma unroll
        for (int dj = 0; dj < 3; ++dj)
#pragma unroll
            for (int q = 0; q < 4; ++q) {
                int p = di * 3 + dj;
                float a = Wt[(p * 16 + ch * 8 + 2 * q) * 32 + f];
                float c = Wt[(p * 16 + ch * 8 + 2 * q + 1) * 32 + f];
                wh[di][dj][q] = pkrtz(a, c);
            }

    const _Float16* xb = xh + ((size_t)b * 128 * 128 + (size_t)j) * 16 + ch * 8;
    float* op = out + (((size_t)b * 126 + i0) * 126 + j) * 32 + f;

    const _Float16 HINF = (_Float16)__builtin_huge_valf();
    h2 accB = {HINF, HINF};  // partial min for output row r-1
    h2 accC = {HINF, HINF};  // partial min for output row r-2

    // pipeline register: raw 16B spans for rows, rotated each iteration
    float4 pre[3];
    {
        const _Float16* xr = xb + (size_t)i0 * 2048;
#pragma unroll
        for (int dj = 0; dj < 3; ++dj)
            pre[dj] = *reinterpret_cast<const float4*>(xr + dj * 16);
    }

    auto body = [&](int r, bool do_prefetch, bool do_store) {
        // consume current row from pipeline regs (free: register renaming)
        h2 hx[12];
#pragma unroll
        for (int dj = 0; dj < 3; ++dj) {
            const h2* p = reinterpret_cast<const h2*>(&pre[dj]);
            hx[dj * 4 + 0] = p[0];
            hx[dj * 4 + 1] = p[1];
            hx[dj * 4 + 2] = p[2];
            hx[dj * 4 + 3] = p[3];
        }
        // issue next row's loads BEFORE the math (latency cover ~1 iter)
        if (do_prefetch) {
            const _Float16* xr = xb + (size_t)(i0 + r + 1) * 2048;
#pragma unroll
            for (int dj = 0; dj < 3; ++dj)
                pre[dj] = *reinterpret_cast<const float4*>(xr + dj * 16);
        }

        h2 n0 = rowmin(hx, wh[0]);
        h2 n1 = rowmin(hx, wh[1]);
        h2 n2 = rowmin(hx, wh[2]);

        h2 fin2 = hmin2(accC, n2);  // output row r-2 complete
        accC = hmin2(accB, n1);
        accB = n0;

        if (do_store) {
            _Float16 vm = fin2[0] < fin2[1] ? fin2[0] : fin2[1];  // v_min_f16
            float v = (float)vm;
            v = fminf(v, __shfl_xor(v, 32));  // merge c-halves (lanes tid^32)
            if (writer)
                op[(size_t)(r - 2) * (126 * 32)] = v;
        }
    };

    body(0, true, false);   // input row i0+0, prefetch i0+1
    body(1, true, false);   // input row i0+1, prefetch i0+2
#pragma unroll 2
    for (int r = 2; r < TI + 1; ++r)   // r = 2..21: prefetch i0+r+1 <= i0+22
        body(r, true, true);
    body(TI + 1, false, true);         // last row i0+22: no prefetch (no OOB)
}

// ---- fallback (ws too small): in-kernel conversion, R3-style ----
__global__ __launch_bounds__(256) void erosion_kernel(
    const float* __restrict__ x, const float* __restrict__ Wt,
    float* __restrict__ out)
{
    const int tid = threadIdx.x;
    const int f  = tid & 31;
    const int ch = (tid >> 5) & 1;
    const int jt = tid >> 6;
    const int b  = blockIdx.z;
    const int i0 = blockIdx.y * TI;
    int j = blockIdx.x * 4 + jt;
    const bool jvalid = (j < 126);
    if (!jvalid) j = 125;

    h2 wh[3][3][4];
#pragma unroll
    for (int di = 0; di < 3; ++di)
#pragma unroll
        for (int dj = 0; dj < 3; ++dj)
#pragma unroll
            for (int q = 0; q < 4; ++q) {
                int p = di * 3 + dj;
                float a = Wt[(p * 16 + ch * 8 + 2 * q) * 32 + f];
                float c = Wt[(p * 16 + ch * 8 + 2 * q + 1) * 32 + f];
                wh[di][dj][q] = pkrtz(a, c);
            }

    const float* xb = x + ((size_t)b * 128 * 128 + (size_t)j) * 16 + ch * 8;
    float* op = out + (((size_t)b * 126 + i0) * 126 + j) * 32 + f;

    const _Float16 HINF = (_Float16)__builtin_huge_valf();
    h2 accB = {HINF, HINF};
    h2 accC = {HINF, HINF};

#pragma unroll 2
    for (int r = 0; r < TI + 2; ++r) {
        const float* xr = xb + (size_t)(i0 + r) * 2048;
        h2 hx[12];
#pragma unroll
        for (int dj = 0; dj < 3; ++dj) {
            float4 lo = *reinterpret_cast<const float4*>(xr + dj * 16);
            float4 hi = *reinterpret_cast<const float4*>(xr + dj * 16 + 4);
            hx[dj * 4 + 0] = pkrtz(lo.x, lo.y);
            hx[dj * 4 + 1] = pkrtz(lo.z, lo.w);
            hx[dj * 4 + 2] = pkrtz(hi.x, hi.y);
            hx[dj * 4 + 3] = pkrtz(hi.z, hi.w);
        }

        h2 n0 = rowmin(hx, wh[0]);
        h2 n1 = rowmin(hx, wh[1]);
        h2 n2 = rowmin(hx, wh[2]);

        h2 fin2 = hmin2(accC, n2);
        accC = hmin2(accB, n1);
        accB = n0;

        if (r >= 2) {
            _Float16 vm = fin2[0] < fin2[1] ? fin2[0] : fin2[1];
            float v = (float)vm;
            v = fminf(v, __shfl_xor(v, 32));
            if (jvalid && ch == 0)
                op[(size_t)(r - 2) * (126 * 32)] = v;
        }
    }
}

extern "C" void kernel_launch(void* const* d_in, const int* in_sizes, int n_in,
                              void* d_out, int out_size, void* d_ws, size_t ws_size,
                              hipStream_t stream) {
    const float* x  = (const float*)d_in[0];  // 16*128*128*16
    const float* Wt = (const float*)d_in[1];  // 3*3*16*32
    float* out = (float*)d_out;               // 16*126*126*32

    const size_t xelems = (size_t)16 * 128 * 128 * 16;  // 4,194,304
    dim3 grid(32, 6, 16);   // 3072 blocks (R3 config: empirically best)
    dim3 block(256);

    if (ws_size >= xelems * sizeof(_Float16)) {
        _Float16* xh = (_Float16*)d_ws;
        cvt_kernel<<<dim3(xelems / (256 * 8)), block, 0, stream>>>(x, xh);
        erosion_h_kernel<<<grid, block, 0, stream>>>(xh, Wt, out);
    } else {
        erosion_kernel<<<grid, block, 0, stream>>>(x, Wt, out);
    }
}